// Round 1
// baseline (5137.926 us; speedup 1.0000x reference)
//
#include <hip/hip_runtime.h>
#include <hip/hip_bf16.h>

// WeightedGNN forward, MI355X. Round 6: persistent cooperative kernel.
// The 64-step recurrence is independent per batch (einsum sums over i within b),
// so the 128-dispatch loop (23.5 us/iter, ~4x the compute+L2 floor) is replaced by
// ONE kernel: 128 blocks x 1024 thr = 8 blocks/batch, batch b pinned to XCD b%8.
// Per iter: phase P (proj+LN, block q = rel-chunk hh) -> 8-block spin barrier ->
// phase A (agg+gate+Wout, blocks q<4 = old k_agg verbatim) -> barrier.
// Math is op-for-op identical to the previous passing kernel (bitwise-stable).
// B=16, L=64, D=256, NRELS=8.

#define DD 256
#define LLEN 64
#define BBAT 16
#define NROWS 1024   // B*L

typedef __attribute__((ext_vector_type(8))) short short8;   // 8 bf16 = 4 VGPRs
typedef __attribute__((ext_vector_type(4))) float f32x4;

__device__ inline unsigned short f2bf(float x) {
    unsigned int u = __float_as_uint(x);
    unsigned int r = (u + 0x7fffu + ((u >> 16) & 1u)) >> 16;
    return (unsigned short)r;
}

// ---------------- per-batch 8-block barrier (agent-scope atomics) -------------
// Monotonic generation counter; leader resets ctr then releases gen.
// Relaxed polls hit the coherence point (no per-poll cache dump); the
// __threadfence pair provides the wbl2/inv for the bulk data.
__device__ inline void batch_bar(int* ctr, int* gen) {
    __syncthreads();
    if (threadIdx.x == 0) {
        int g = __hip_atomic_load(gen, __ATOMIC_RELAXED, __HIP_MEMORY_SCOPE_AGENT);
        __threadfence();   // release my block's Pf/h writes to the coherence point
        int prev = __hip_atomic_fetch_add(ctr, 1, __ATOMIC_ACQ_REL, __HIP_MEMORY_SCOPE_AGENT);
        if (prev == 7) {
            __hip_atomic_store(ctr, 0, __ATOMIC_RELAXED, __HIP_MEMORY_SCOPE_AGENT);
            __hip_atomic_store(gen, g + 1, __ATOMIC_RELEASE, __HIP_MEMORY_SCOPE_AGENT);
        } else {
            int spins = 0;
            while (__hip_atomic_load(gen, __ATOMIC_RELAXED, __HIP_MEMORY_SCOPE_AGENT) == g) {
                __builtin_amdgcn_s_sleep(1);
                if (++spins > (1 << 24)) break;   // escape hatch; never hit when co-resident
            }
        }
        __threadfence();   // acquire: invalidate stale cached data
    }
    __syncthreads();
}

// ---------------- fused one-time prep: cvtW | cvtA | cvtWo | inproj | setup ---
__global__ __launch_bounds__(256) void k_prep(
    const int* __restrict__ tokens, const float* __restrict__ A,
    const float* __restrict__ emb,
    const float* __restrict__ Wp, const float* __restrict__ Wi,
    const float* __restrict__ bi, const float* __restrict__ Wo,
    unsigned short* __restrict__ Wf, unsigned short* __restrict__ Af,
    unsigned short* __restrict__ Wof,
    float* __restrict__ shiftb, float* __restrict__ scaleb, float* __restrict__ projx,
    int* __restrict__ lengths, int* __restrict__ bar)
{
    __shared__ float xs[8][DD];
    const int tid = threadIdx.x;
    const int bid = blockIdx.x;

    if (bid < 256) {
        // ---- W_proj [256][2048] fp32 -> bf16 B-fragment layout ----
        int t = bid * 256 + tid;   // 65536
        int l = t & 63; int rest = t >> 6;
        int tk = rest & 7; rest >>= 3;
        int tn = rest & 15; int hh = rest >> 4;
        int kbase = tk * 32 + (l >> 4) * 8;
        int n = hh * 256 + tn * 16 + (l & 15);
        union { short8 v; unsigned short u[8]; } pk;
#pragma unroll
        for (int j = 0; j < 8; ++j) pk.u[j] = f2bf(Wp[(kbase + j) * 2048 + n]);
        *(short8*)(Wf + (long)t * 8) = pk.v;
    } else if (bid < 512) {
        // ---- A_rels -> bf16 A-fragment layout, K-order k = h*64 + i ----
        int t = (bid - 256) * 256 + tid;   // 65536
        int lane = t & 63;
        int tk = (t >> 6) & 15;
        int jg = (t >> 10) & 3;
        int b  = t >> 12;
        int j = jg * 16 + (lane & 15);
        int kbase = tk * 32 + (lane >> 4) * 8;
        int h  = kbase >> 6;
        int i0 = kbase & 63;
        union { short8 v; unsigned short u[8]; } pk;
#pragma unroll
        for (int jj = 0; jj < 8; ++jj)
            pk.u[jj] = f2bf(A[((long)(b * 64 + i0 + jj) * 64 + j) * 8 + h]);
        *(short8*)(Af + (long)t * 8) = pk.v;
    } else if (bid < 544) {
        // ---- W_out [256][256] fp32 -> bf16 B-fragment layout ----
        int t = (bid - 512) * 256 + tid;   // 8192
        int lane = t & 63;
        int tk = (t >> 6) & 7;
        int nt = t >> 9;
        int kbase = tk * 32 + (lane >> 4) * 8;
        int n = nt * 16 + (lane & 15);
        union { short8 v; unsigned short u[8]; } pk;
#pragma unroll
        for (int j = 0; j < 8; ++j) pk.u[j] = f2bf(Wo[(kbase + j) * 256 + n]);
        *(short8*)(Wof + (long)t * 8) = pk.v;
    } else if (bid < 928) {
        // ---- in_proj: gather emb + [1024x256]@[256x768], 384 blocks ----
        // (was 128 blocks / 3 cols per thread at 5% occupancy, 42 us; now
        //  1 W-column per thread, 3x the blocks -> latency amortized)
        int lb = bid - 544;
        int rowx = lb & 127, nc = lb >> 7;    // nc: 0=shift 1=scale 2=projx
        const int row0 = rowx * 8;
        for (int r = 0; r < 8; ++r) {
            int row = row0 + r;
            int b = row >> 6, l = row & 63;
            int tok = tokens[l * BBAT + b];
            xs[r][tid] = emb[(long)tok * DD + tid];
        }
        __syncthreads();
        const int col = nc * 256 + tid;
        float a[8];
#pragma unroll
        for (int r = 0; r < 8; ++r) a[r] = 0.f;
#pragma unroll 4
        for (int k = 0; k < DD; ++k) {
            float wv = Wi[k * 768 + col];
#pragma unroll
            for (int r = 0; r < 8; ++r) a[r] = fmaf(xs[r][k], wv, a[r]);
        }
        const float bia = bi[col];
        float* dst = (nc == 0) ? shiftb : (nc == 1) ? scaleb : projx;
#pragma unroll
        for (int r = 0; r < 8; ++r) dst[(row0 + r) * DD + tid] = a[r] + bia;
    } else {
        // ---- lengths[b] + barrier-state init ----
        if (tid < 32) bar[tid] = 0;
        if (tid < BBAT) {
            int c = 0;
            for (int l = 0; l < LLEN; ++l) c += (tokens[l * BBAT + tid] != 0) ? 1 : 0;
            lengths[tid] = c;
        }
    }
}

// ---------------- persistent 64-iteration recurrence kernel -------------------
// grid 128: bid = (b&7) + 8*q + 64*(b>>3)  ->  batch b on XCD b%8, q in [0,8).
// Phase P: block q = rel-chunk hh; 16 waves = 4 groups (ig = w>>2) x 4 waves (wv),
//          each group == one old k_proj block (hh, ig). LDS Cs4/part4.
// Phase A: blocks q<4 run old k_agg body with jg=q (16 waves, nt=w).
__global__ __launch_bounds__(1024) void k_loop(
    const unsigned short* __restrict__ Af,     // [16][4][16][64][8]
    unsigned short* __restrict__ Pf,           // [16][16 tk1][16 nt][64][8]
    const float* __restrict__ projx,
    const float* __restrict__ shiftb,
    const float* __restrict__ scaleb,
    const unsigned short* __restrict__ Wf,     // fragment-packed W_proj
    const float* __restrict__ bp,              // [2048]
    const unsigned short* __restrict__ Wof,    // [16 nt][8 tk][64][8]
    const float* __restrict__ bout,
    const int* __restrict__ lengths,
    float* __restrict__ h_out,                 // [1024][256] fp32 (last iter)
    unsigned short* __restrict__ h_bf,         // [1024][256] bf16
    const float* __restrict__ root,
    float* __restrict__ out,
    int* __restrict__ bar)
{
    __shared__ float Cs4[4][16][260];            // phase P: 65 KB
    __shared__ float part4[4][4][16][2];         // phase P: 2 KB
    __shared__ float CsA[16][260];               // phase A: 16.3 KB
    __shared__ unsigned short hsb[16][264];      // phase A: 8.3 KB
    __shared__ float partA[16][4][2];            // phase A: 0.5 KB

    const int t = threadIdx.x;
    const int w = t >> 6, lane = t & 63;
    const int bid = blockIdx.x;
    const int t2 = bid >> 3;
    const int q = t2 & 7;
    const int b = (bid & 7) + 8 * (t2 >> 3);
    const int hh = q;
    int* ctr = bar + b * 2;
    int* gen = bar + b * 2 + 1;
    const int len_b = lengths[b];

    // hoisted phase-P constants
    const int ig = w >> 2, wv = w & 3;
    const int row0 = b * 64 + ig * 16;
    const unsigned short* aRow = h_bf + (row0 + (lane & 15)) * DD + (lane >> 4) * 8;
    const unsigned short* wBase = Wf + ((long)(hh * 16 + wv * 4) * 8) * 512 + lane * 8;
    const int g2 = t >> 8;            // == ig for this thread
    const int tc = t & 255;           // col within 256-chunk (== wv*64 + lane)
    const float biasP = bp[hh * 256 + tc];
    // hoisted phase-A constants
    const int d = t & 255;
    const int rbase = (w >> 2) * 4;
    const int dseg = w & 3;
    const float bo_d = bout[d];

    for (int it = 0; it < 64; ++it) {
        // ================= phase P: Pf = LN_perchunk(h @ W_proj + bp) =========
        {
            f32x4 acc[4];
#pragma unroll
            for (int tn = 0; tn < 4; ++tn) acc[tn] = (f32x4){0.f, 0.f, 0.f, 0.f};
            short8 a8[8];
#pragma unroll
            for (int tk = 0; tk < 8; ++tk) a8[tk] = *(const short8*)(aRow + tk * 32);
#pragma unroll
            for (int tk = 0; tk < 8; ++tk) {
#pragma unroll
                for (int tn = 0; tn < 4; ++tn) {
                    short8 bbv = *(const short8*)(wBase + (long)(tn * 8 + tk) * 512);
                    acc[tn] = __builtin_amdgcn_mfma_f32_16x16x32_bf16(a8[tk], bbv, acc[tn], 0, 0, 0);
                }
            }
#pragma unroll
            for (int tn = 0; tn < 4; ++tn) {
                int n = wv * 64 + tn * 16 + (lane & 15);
                int m0 = (lane >> 4) * 4;
#pragma unroll
                for (int r = 0; r < 4; ++r) Cs4[ig][m0 + r][n] = acc[tn][r];
            }
        }
        __syncthreads();
        {
            float vals[16];
#pragma unroll
            for (int r = 0; r < 16; ++r) vals[r] = Cs4[g2][r][tc] + biasP;
            for (int r = 0; r < 16; ++r) {
                float s = vals[r], ss = vals[r] * vals[r];
#pragma unroll
                for (int m = 32; m >= 1; m >>= 1) { s += __shfl_xor(s, m); ss += __shfl_xor(ss, m); }
                if (lane == 0) { part4[g2][wv][r][0] = s; part4[g2][wv][r][1] = ss; }
            }
            __syncthreads();
            float normed[16];
#pragma unroll
            for (int r = 0; r < 16; ++r) {
                float s  = part4[g2][0][r][0] + part4[g2][1][r][0] + part4[g2][2][r][0] + part4[g2][3][r][0];
                float ss = part4[g2][0][r][1] + part4[g2][1][r][1] + part4[g2][2][r][1] + part4[g2][3][r][1];
                float mean = s * (1.f / 256.f);
                float var  = ss * (1.f / 256.f) - mean * mean;
                float rstd = rsqrtf(var + 1e-5f);
                normed[r] = (vals[r] - mean) * rstd;
            }
            const int ibase = g2 * 16;
#pragma unroll
            for (int g = 0; g < 2; ++g) {
                int k0 = hh * 64 + ibase + g * 8;
                int tk1 = k0 >> 5;
                int lane_s = ((k0 >> 3) & 3) * 16 + (tc & 15);
                long off = (long)b * 131072 + tk1 * 8192 + (tc >> 4) * 512 + lane_s * 8;
                union { short8 v; unsigned short u[8]; } pk;
#pragma unroll
                for (int jj = 0; jj < 8; ++jj) pk.u[jj] = f2bf(normed[g * 8 + jj]);
                *(short8*)(Pf + off) = pk.v;
            }
        }
        batch_bar(ctr, gen);   // Pf[b] complete & visible

        // ================= phase A: agg + gate + W_out (blocks q<4) ===========
        if (q < 4) {
            const int jg = q;
            const unsigned short* ab = Af + ((long)(b * 4 + jg) * 16) * 512 + lane * 8;
            const unsigned short* pb = Pf + (long)b * 131072 + w * 512 + lane * 8;
            short8 bfr[16];
#pragma unroll
            for (int tk = 0; tk < 16; ++tk)
                bfr[tk] = *(const short8*)(pb + (long)tk * 8192);
            f32x4 acc = (f32x4){0.f, 0.f, 0.f, 0.f};
#pragma unroll
            for (int tk = 0; tk < 16; ++tk) {
                short8 a = *(const short8*)(ab + (long)tk * 512);
                acc = __builtin_amdgcn_mfma_f32_16x16x32_bf16(a, bfr[tk], acc, 0, 0, 0);
            }
            {
                int n = w * 16 + (lane & 15);
                int m0 = (lane >> 4) * 4;
#pragma unroll
                for (int r = 0; r < 4; ++r) CsA[m0 + r][n] = acc[r];
            }
            __syncthreads();

            float tv[4];
#pragma unroll
            for (int ri = 0; ri < 4; ++ri) {
                int row = b * 64 + jg * 16 + rbase + ri;
                float lin = CsA[rbase + ri][d];
                float shr = lin - tanhf(lin);
                tv[ri] = projx[row * DD + d] + shr;
            }
#pragma unroll
            for (int ri = 0; ri < 4; ++ri) {
                float s = tv[ri], ss = tv[ri] * tv[ri];
#pragma unroll
                for (int m = 32; m >= 1; m >>= 1) { s += __shfl_xor(s, m); ss += __shfl_xor(ss, m); }
                if (lane == 0) { partA[rbase + ri][dseg][0] = s; partA[rbase + ri][dseg][1] = ss; }
            }
            __syncthreads();
#pragma unroll
            for (int ri = 0; ri < 4; ++ri) {
                int r = rbase + ri;
                int row = b * 64 + jg * 16 + r;
                float s  = partA[r][0][0] + partA[r][1][0] + partA[r][2][0] + partA[r][3][0];
                float ss = partA[r][0][1] + partA[r][1][1] + partA[r][2][1] + partA[r][3][1];
                float mean = s * (1.f / 256.f);
                float var  = ss * (1.f / 256.f) - mean * mean;
                float rstd = rsqrtf(var + 1e-5f);
                float nv = (tv[ri] - mean) * rstd;
                float hv = fmaf(shiftb[row * DD + d], nv, scaleb[row * DD + d]);
                hsb[r][d] = f2bf(fmaxf(hv, 0.f));
            }
            __syncthreads();

            f32x4 acc2 = (f32x4){0.f, 0.f, 0.f, 0.f};
#pragma unroll
            for (int tk = 0; tk < 8; ++tk) {
                short8 a = *(const short8*)(&hsb[lane & 15][tk * 32 + (lane >> 4) * 8]);
                short8 wf = *(const short8*)(Wof + (long)(w * 8 + tk) * 512 + lane * 8);
                acc2 = __builtin_amdgcn_mfma_f32_16x16x32_bf16(a, wf, acc2, 0, 0, 0);
            }
            {
                int n = w * 16 + (lane & 15);
                int m0 = (lane >> 4) * 4;
#pragma unroll
                for (int r = 0; r < 4; ++r) CsA[m0 + r][n] = acc2[r];
            }
            __syncthreads();
            const int i_val = 64 - it;
            const bool maskz = (i_val > len_b);
#pragma unroll
            for (int ri = 0; ri < 4; ++ri) {
                int r = rbase + ri;
                int row = b * 64 + jg * 16 + r;
                float y = tanhf(CsA[r][d] + bo_d);
                float ym = maskz ? 0.f : y;
                h_bf[row * DD + d] = f2bf(ym);
                if (it == 63) h_out[row * DD + d] = ym;
            }
        }
        batch_bar(ctr, gen);   // h[b] complete & visible for next phase P
    }

    // ---- final: out[b,d] = sum_i h[b,i,d] * root[b,i] ----
    if (q == 0 && t < DD) {
        float accf = 0.f;
        for (int i = 0; i < LLEN; ++i)
            accf = fmaf(h_out[(b * 64 + i) * DD + t], root[b * 64 + i], accf);
        out[b * DD + t] = accf;
    }
}

extern "C" void kernel_launch(void* const* d_in, const int* in_sizes, int n_in,
                              void* d_out, int out_size, void* d_ws, size_t ws_size,
                              hipStream_t stream)
{
    const int*   tokens = (const int*)  d_in[0];
    const float* A      = (const float*)d_in[1];
    const float* root   = (const float*)d_in[2];
    const float* emb    = (const float*)d_in[3];
    const float* Wp     = (const float*)d_in[4];
    const float* bp     = (const float*)d_in[5];
    const float* Wi     = (const float*)d_in[6];
    const float* bi     = (const float*)d_in[7];
    const float* Wo     = (const float*)d_in[8];
    const float* bo     = (const float*)d_in[9];
    float* out = (float*)d_out;

    char* ws = (char*)d_ws;
    int*   lengths = (int*)(ws + 0);
    int*   bar     = (int*)(ws + 256);       // 32 ints, inside lengths' 1 KB slot
    float* shiftb  = (float*)(ws + 1024);
    float* scaleb  = shiftb + NROWS * DD;
    float* projx   = scaleb + NROWS * DD;
    float* h_out   = projx  + NROWS * DD;                          // 1 MB fp32
    unsigned short* h_bf = (unsigned short*)(h_out + NROWS * DD);  // 512 KB
    unsigned short* Wf   = h_bf + NROWS * DD;                      // 1 MB
    unsigned short* Pf   = Wf + 524288;                            // 4 MB
    unsigned short* Af   = Pf + 2097152;                           // 1 MB
    unsigned short* Wof  = Af + 524288;                            // 128 KB

    hipMemsetAsync(h_bf, 0, (size_t)NROWS * DD * sizeof(unsigned short), stream);
    k_prep<<<929, 256, 0, stream>>>(tokens, A, emb, Wp, Wi, bi, Wo,
                                    Wf, Af, Wof, shiftb, scaleb, projx, lengths, bar);
    void* kargs[] = { (void*)&Af, (void*)&Pf, (void*)&projx, (void*)&shiftb, (void*)&scaleb,
                      (void*)&Wf, (void*)&bp, (void*)&Wof, (void*)&bo, (void*)&lengths,
                      (void*)&h_out, (void*)&h_bf, (void*)&root, (void*)&out, (void*)&bar };
    hipLaunchCooperativeKernel((const void*)k_loop, dim3(128), dim3(1024), kargs, 0, stream);
}

// Round 2
// 4859.012 us; speedup vs baseline: 1.0574x; 1.0574x over previous
//
#include <hip/hip_runtime.h>
#include <hip/hip_bf16.h>

// WeightedGNN forward, MI355X. Round 7: persistent cooperative kernel,
// fence-free sync. Round 6 failed because __threadfence() (agent scope)
// emits buffer_wbl2+buffer_inv -> full per-XCD L2 wipe at every barrier
// (FETCH_SIZE 3.4 GB, 67 us/iter of HBM refetch). Fix: cross-block data
// (Pf, h_bf, h_out) moves via agent-scope RELAXED atomics (sc0/sc1 bits:
// bypass L1/L2, coherent at MALL) so NO fence is needed; barrier is a
// relaxed fetch_add + poll after s_waitcnt vmcnt(0). Read-only data (Wf,
// Af, Wof, projx/shiftb/scaleb) uses plain cached loads and now stays
// L2-warm across all 64 iterations (no inv ever executes).
// Math is op-for-op identical to the round-5 passing kernel.
// B=16, L=64, D=256, NRELS=8.

#define DD 256
#define LLEN 64
#define BBAT 16
#define NROWS 1024   // B*L

typedef __attribute__((ext_vector_type(8))) short short8;   // 8 bf16 = 4 VGPRs
typedef __attribute__((ext_vector_type(4))) float f32x4;
typedef unsigned long long u64;

__device__ inline unsigned short f2bf(float x) {
    unsigned int u = __float_as_uint(x);
    unsigned int r = (u + 0x7fffu + ((u >> 16) & 1u)) >> 16;
    return (unsigned short)r;
}

// ---- coherent (agent-scope, relaxed) 16B/2B/4B accesses: sc0 sc1, no fences --
__device__ inline short8 ld_coh16(const unsigned short* p) {
    union { short8 v; u64 q[2]; } r;
    r.q[0] = __hip_atomic_load((const u64*)p,     __ATOMIC_RELAXED, __HIP_MEMORY_SCOPE_AGENT);
    r.q[1] = __hip_atomic_load((const u64*)p + 1, __ATOMIC_RELAXED, __HIP_MEMORY_SCOPE_AGENT);
    return r.v;
}
__device__ inline void st_coh16(unsigned short* p, short8 v) {
    union { short8 v; u64 q[2]; } r; r.v = v;
    __hip_atomic_store((u64*)p,     r.q[0], __ATOMIC_RELAXED, __HIP_MEMORY_SCOPE_AGENT);
    __hip_atomic_store((u64*)p + 1, r.q[1], __ATOMIC_RELAXED, __HIP_MEMORY_SCOPE_AGENT);
}
__device__ inline void st_coh_u16(unsigned short* p, unsigned short v) {
    __hip_atomic_store(p, v, __ATOMIC_RELAXED, __HIP_MEMORY_SCOPE_AGENT);
}
__device__ inline void st_coh_f32(float* p, float v) {
    __hip_atomic_store(p, v, __ATOMIC_RELAXED, __HIP_MEMORY_SCOPE_AGENT);
}
__device__ inline float ld_coh_f32(const float* p) {
    return __hip_atomic_load(p, __ATOMIC_RELAXED, __HIP_MEMORY_SCOPE_AGENT);
}

// ---------------- per-batch 8-block barrier (fence-free) ----------------------
// Data crossing the barrier uses sc1 accesses (coherent at MALL), so no
// wbl2/inv is needed. The preceding __syncthreads drains each wave's vmcnt
// (compiler-inserted s_waitcnt before s_barrier); the explicit vmcnt(0) on
// thread 0 is belt-and-suspenders. All atomics relaxed -> no cache ops.
__device__ inline void batch_bar(int* ctr, int* gen) {
    __syncthreads();
    if (threadIdx.x == 0) {
        asm volatile("s_waitcnt vmcnt(0)" ::: "memory");
        int g = __hip_atomic_load(gen, __ATOMIC_RELAXED, __HIP_MEMORY_SCOPE_AGENT);
        int prev = __hip_atomic_fetch_add(ctr, 1, __ATOMIC_RELAXED, __HIP_MEMORY_SCOPE_AGENT);
        if (prev == 7) {
            __hip_atomic_store(ctr, 0, __ATOMIC_RELAXED, __HIP_MEMORY_SCOPE_AGENT);
            __hip_atomic_store(gen, g + 1, __ATOMIC_RELAXED, __HIP_MEMORY_SCOPE_AGENT);
        } else {
            int spins = 0;
            while (__hip_atomic_load(gen, __ATOMIC_RELAXED, __HIP_MEMORY_SCOPE_AGENT) == g) {
                __builtin_amdgcn_s_sleep(2);
                if (++spins > (1 << 22)) break;   // escape hatch; never hit when co-resident
            }
        }
    }
    __syncthreads();
    __builtin_amdgcn_sched_barrier(0);   // pin: no code motion across the barrier
}

// ---------------- fused one-time prep: cvtW | cvtA | cvtWo | inproj | setup ---
__global__ __launch_bounds__(256) void k_prep(
    const int* __restrict__ tokens, const float* __restrict__ A,
    const float* __restrict__ emb,
    const float* __restrict__ Wp, const float* __restrict__ Wi,
    const float* __restrict__ bi, const float* __restrict__ Wo,
    unsigned short* __restrict__ Wf, unsigned short* __restrict__ Af,
    unsigned short* __restrict__ Wof,
    float* __restrict__ shiftb, float* __restrict__ scaleb, float* __restrict__ projx,
    int* __restrict__ lengths, int* __restrict__ bar)
{
    __shared__ float xs[8][DD];
    const int tid = threadIdx.x;
    const int bid = blockIdx.x;

    if (bid < 256) {
        // ---- W_proj [256][2048] fp32 -> bf16 B-fragment layout ----
        int t = bid * 256 + tid;   // 65536
        int l = t & 63; int rest = t >> 6;
        int tk = rest & 7; rest >>= 3;
        int tn = rest & 15; int hh = rest >> 4;
        int kbase = tk * 32 + (l >> 4) * 8;
        int n = hh * 256 + tn * 16 + (l & 15);
        union { short8 v; unsigned short u[8]; } pk;
#pragma unroll
        for (int j = 0; j < 8; ++j) pk.u[j] = f2bf(Wp[(kbase + j) * 2048 + n]);
        *(short8*)(Wf + (long)t * 8) = pk.v;
    } else if (bid < 512) {
        // ---- A_rels -> bf16 A-fragment layout, K-order k = h*64 + i ----
        int t = (bid - 256) * 256 + tid;   // 65536
        int lane = t & 63;
        int tk = (t >> 6) & 15;
        int jg = (t >> 10) & 3;
        int b  = t >> 12;
        int j = jg * 16 + (lane & 15);
        int kbase = tk * 32 + (lane >> 4) * 8;
        int h  = kbase >> 6;
        int i0 = kbase & 63;
        union { short8 v; unsigned short u[8]; } pk;
#pragma unroll
        for (int jj = 0; jj < 8; ++jj)
            pk.u[jj] = f2bf(A[((long)(b * 64 + i0 + jj) * 64 + j) * 8 + h]);
        *(short8*)(Af + (long)t * 8) = pk.v;
    } else if (bid < 544) {
        // ---- W_out [256][256] fp32 -> bf16 B-fragment layout ----
        int t = (bid - 512) * 256 + tid;   // 8192
        int lane = t & 63;
        int tk = (t >> 6) & 7;
        int nt = t >> 9;
        int kbase = tk * 32 + (lane >> 4) * 8;
        int n = nt * 16 + (lane & 15);
        union { short8 v; unsigned short u[8]; } pk;
#pragma unroll
        for (int j = 0; j < 8; ++j) pk.u[j] = f2bf(Wo[(kbase + j) * 256 + n]);
        *(short8*)(Wof + (long)t * 8) = pk.v;
    } else if (bid < 928) {
        // ---- in_proj: gather emb + [1024x256]@[256x768], 384 blocks ----
        int lb = bid - 544;
        int rowx = lb & 127, nc = lb >> 7;    // nc: 0=shift 1=scale 2=projx
        const int row0 = rowx * 8;
        for (int r = 0; r < 8; ++r) {
            int row = row0 + r;
            int b = row >> 6, l = row & 63;
            int tok = tokens[l * BBAT + b];
            xs[r][tid] = emb[(long)tok * DD + tid];
        }
        __syncthreads();
        const int col = nc * 256 + tid;
        float a[8];
#pragma unroll
        for (int r = 0; r < 8; ++r) a[r] = 0.f;
#pragma unroll 4
        for (int k = 0; k < DD; ++k) {
            float wv = Wi[k * 768 + col];
#pragma unroll
            for (int r = 0; r < 8; ++r) a[r] = fmaf(xs[r][k], wv, a[r]);
        }
        const float bia = bi[col];
        float* dst = (nc == 0) ? shiftb : (nc == 1) ? scaleb : projx;
#pragma unroll
        for (int r = 0; r < 8; ++r) dst[(row0 + r) * DD + tid] = a[r] + bia;
    } else {
        // ---- lengths[b] + barrier-state init ----
        if (tid < 32) bar[tid] = 0;
        if (tid < BBAT) {
            int c = 0;
            for (int l = 0; l < LLEN; ++l) c += (tokens[l * BBAT + tid] != 0) ? 1 : 0;
            lengths[tid] = c;
        }
    }
}

// ---------------- persistent 64-iteration recurrence kernel -------------------
// grid 128: bid = (b&7) + 8*q + 64*(b>>3)  ->  batch b on XCD b%8, q in [0,8).
// Phase P: block q = rel-chunk hh; 16 waves = 4 groups (ig) x 4 waves (wv).
// Phase A: blocks q<4 run the agg/gate/Wout body with jg=q (16 waves, nt=w).
// Cross-phase data (h_bf, Pf, h_out) via sc1 coherent accesses only.
__global__ __launch_bounds__(1024) void k_loop(
    const unsigned short* __restrict__ Af,     // [16][4][16][64][8]
    unsigned short* __restrict__ Pf,           // [16][16 tk1][16 nt][64][8]
    const float* __restrict__ projx,
    const float* __restrict__ shiftb,
    const float* __restrict__ scaleb,
    const unsigned short* __restrict__ Wf,     // fragment-packed W_proj
    const float* __restrict__ bp,              // [2048]
    const unsigned short* __restrict__ Wof,    // [16 nt][8 tk][64][8]
    const float* __restrict__ bout,
    const int* __restrict__ lengths,
    float* __restrict__ h_out,                 // [1024][256] fp32 (last iter)
    unsigned short* __restrict__ h_bf,         // [1024][256] bf16
    const float* __restrict__ root,
    float* __restrict__ out,
    int* __restrict__ bar)
{
    __shared__ float Cs4[4][16][260];            // phase P: 65 KB
    __shared__ float part4[4][4][16][2];         // phase P: 2 KB
    __shared__ float CsA[16][260];               // phase A: 16.3 KB
    __shared__ unsigned short hsb[16][264];      // phase A: 8.3 KB
    __shared__ float partA[16][4][2];            // phase A: 0.5 KB

    const int t = threadIdx.x;
    const int w = t >> 6, lane = t & 63;
    const int bid = blockIdx.x;
    const int t2 = bid >> 3;
    const int q = t2 & 7;
    const int b = (bid & 7) + 8 * (t2 >> 3);
    const int hh = q;
    int* ctr = bar + b * 2;
    int* gen = bar + b * 2 + 1;
    const int len_b = lengths[b];

    // hoisted phase-P constants
    const int ig = w >> 2, wv = w & 3;
    const int row0 = b * 64 + ig * 16;
    const unsigned short* aRow = h_bf + (row0 + (lane & 15)) * DD + (lane >> 4) * 8;
    const unsigned short* wBase = Wf + ((long)(hh * 16 + wv * 4) * 8) * 512 + lane * 8;
    const int g2 = t >> 8;            // == ig for this thread
    const int tc = t & 255;           // col within 256-chunk (== wv*64 + lane)
    const float biasP = bp[hh * 256 + tc];
    // hoisted phase-A constants
    const int d = t & 255;
    const int rbase = (w >> 2) * 4;
    const int dseg = w & 3;
    const float bo_d = bout[d];

    for (int it = 0; it < 64; ++it) {
        // ================= phase P: Pf = LN_perchunk(h @ W_proj + bp) =========
        {
            f32x4 acc[4];
#pragma unroll
            for (int tn = 0; tn < 4; ++tn) acc[tn] = (f32x4){0.f, 0.f, 0.f, 0.f};
            short8 a8[8];
#pragma unroll
            for (int tk = 0; tk < 8; ++tk) a8[tk] = ld_coh16(aRow + tk * 32);
#pragma unroll
            for (int tk = 0; tk < 8; ++tk) {
#pragma unroll
                for (int tn = 0; tn < 4; ++tn) {
                    short8 bbv = *(const short8*)(wBase + (long)(tn * 8 + tk) * 512);
                    acc[tn] = __builtin_amdgcn_mfma_f32_16x16x32_bf16(a8[tk], bbv, acc[tn], 0, 0, 0);
                }
            }
#pragma unroll
            for (int tn = 0; tn < 4; ++tn) {
                int n = wv * 64 + tn * 16 + (lane & 15);
                int m0 = (lane >> 4) * 4;
#pragma unroll
                for (int r = 0; r < 4; ++r) Cs4[ig][m0 + r][n] = acc[tn][r];
            }
        }
        __syncthreads();
        {
            float vals[16];
#pragma unroll
            for (int r = 0; r < 16; ++r) vals[r] = Cs4[g2][r][tc] + biasP;
            for (int r = 0; r < 16; ++r) {
                float s = vals[r], ss = vals[r] * vals[r];
#pragma unroll
                for (int m = 32; m >= 1; m >>= 1) { s += __shfl_xor(s, m); ss += __shfl_xor(ss, m); }
                if (lane == 0) { part4[g2][wv][r][0] = s; part4[g2][wv][r][1] = ss; }
            }
            __syncthreads();
            float normed[16];
#pragma unroll
            for (int r = 0; r < 16; ++r) {
                float s  = part4[g2][0][r][0] + part4[g2][1][r][0] + part4[g2][2][r][0] + part4[g2][3][r][0];
                float ss = part4[g2][0][r][1] + part4[g2][1][r][1] + part4[g2][2][r][1] + part4[g2][3][r][1];
                float mean = s * (1.f / 256.f);
                float var  = ss * (1.f / 256.f) - mean * mean;
                float rstd = rsqrtf(var + 1e-5f);
                normed[r] = (vals[r] - mean) * rstd;
            }
            const int ibase = g2 * 16;
#pragma unroll
            for (int g = 0; g < 2; ++g) {
                int k0 = hh * 64 + ibase + g * 8;
                int tk1 = k0 >> 5;
                int lane_s = ((k0 >> 3) & 3) * 16 + (tc & 15);
                long off = (long)b * 131072 + tk1 * 8192 + (tc >> 4) * 512 + lane_s * 8;
                union { short8 v; unsigned short u[8]; } pk;
#pragma unroll
                for (int jj = 0; jj < 8; ++jj) pk.u[jj] = f2bf(normed[g * 8 + jj]);
                st_coh16(Pf + off, pk.v);
            }
        }
        batch_bar(ctr, gen);   // Pf[b] complete & visible (sc1 path, no fences)

        // ================= phase A: agg + gate + W_out (blocks q<4) ===========
        if (q < 4) {
            const int jg = q;
            const unsigned short* ab = Af + ((long)(b * 4 + jg) * 16) * 512 + lane * 8;
            const unsigned short* pb = Pf + (long)b * 131072 + w * 512 + lane * 8;
            short8 bfr[16];
#pragma unroll
            for (int tk = 0; tk < 16; ++tk)
                bfr[tk] = ld_coh16(pb + (long)tk * 8192);
            f32x4 acc = (f32x4){0.f, 0.f, 0.f, 0.f};
#pragma unroll
            for (int tk = 0; tk < 16; ++tk) {
                short8 a = *(const short8*)(ab + (long)tk * 512);
                acc = __builtin_amdgcn_mfma_f32_16x16x32_bf16(a, bfr[tk], acc, 0, 0, 0);
            }
            {
                int n = w * 16 + (lane & 15);
                int m0 = (lane >> 4) * 4;
#pragma unroll
                for (int r = 0; r < 4; ++r) CsA[m0 + r][n] = acc[r];
            }
            __syncthreads();

            float tv[4];
#pragma unroll
            for (int ri = 0; ri < 4; ++ri) {
                int row = b * 64 + jg * 16 + rbase + ri;
                float lin = CsA[rbase + ri][d];
                float shr = lin - tanhf(lin);
                tv[ri] = projx[row * DD + d] + shr;
            }
#pragma unroll
            for (int ri = 0; ri < 4; ++ri) {
                float s = tv[ri], ss = tv[ri] * tv[ri];
#pragma unroll
                for (int m = 32; m >= 1; m >>= 1) { s += __shfl_xor(s, m); ss += __shfl_xor(ss, m); }
                if (lane == 0) { partA[rbase + ri][dseg][0] = s; partA[rbase + ri][dseg][1] = ss; }
            }
            __syncthreads();
#pragma unroll
            for (int ri = 0; ri < 4; ++ri) {
                int r = rbase + ri;
                int row = b * 64 + jg * 16 + r;
                float s  = partA[r][0][0] + partA[r][1][0] + partA[r][2][0] + partA[r][3][0];
                float ss = partA[r][0][1] + partA[r][1][1] + partA[r][2][1] + partA[r][3][1];
                float mean = s * (1.f / 256.f);
                float var  = ss * (1.f / 256.f) - mean * mean;
                float rstd = rsqrtf(var + 1e-5f);
                float nv = (tv[ri] - mean) * rstd;
                float hv = fmaf(shiftb[row * DD + d], nv, scaleb[row * DD + d]);
                hsb[r][d] = f2bf(fmaxf(hv, 0.f));
            }
            __syncthreads();

            f32x4 acc2 = (f32x4){0.f, 0.f, 0.f, 0.f};
#pragma unroll
            for (int tk = 0; tk < 8; ++tk) {
                short8 a = *(const short8*)(&hsb[lane & 15][tk * 32 + (lane >> 4) * 8]);
                short8 wf = *(const short8*)(Wof + (long)(w * 8 + tk) * 512 + lane * 8);
                acc2 = __builtin_amdgcn_mfma_f32_16x16x32_bf16(a, wf, acc2, 0, 0, 0);
            }
            {
                int n = w * 16 + (lane & 15);
                int m0 = (lane >> 4) * 4;
#pragma unroll
                for (int r = 0; r < 4; ++r) CsA[m0 + r][n] = acc2[r];
            }
            __syncthreads();
            const int i_val = 64 - it;
            const bool maskz = (i_val > len_b);
#pragma unroll
            for (int ri = 0; ri < 4; ++ri) {
                int r = rbase + ri;
                int row = b * 64 + jg * 16 + r;
                float y = tanhf(CsA[r][d] + bo_d);
                float ym = maskz ? 0.f : y;
                st_coh_u16(h_bf + row * DD + d, f2bf(ym));
                if (it == 63) st_coh_f32(h_out + row * DD + d, ym);
            }
        }
        batch_bar(ctr, gen);   // h[b] complete & visible for next phase P
    }

    // ---- final: out[b,d] = sum_i h[b,i,d] * root[b,i] ----
    if (q == 0 && t < DD) {
        float accf = 0.f;
        for (int i = 0; i < LLEN; ++i)
            accf = fmaf(ld_coh_f32(h_out + (b * 64 + i) * DD + t), root[b * 64 + i], accf);
        out[b * DD + t] = accf;
    }
}

extern "C" void kernel_launch(void* const* d_in, const int* in_sizes, int n_in,
                              void* d_out, int out_size, void* d_ws, size_t ws_size,
                              hipStream_t stream)
{
    const int*   tokens = (const int*)  d_in[0];
    const float* A      = (const float*)d_in[1];
    const float* root   = (const float*)d_in[2];
    const float* emb    = (const float*)d_in[3];
    const float* Wp     = (const float*)d_in[4];
    const float* bp     = (const float*)d_in[5];
    const float* Wi     = (const float*)d_in[6];
    const float* bi     = (const float*)d_in[7];
    const float* Wo     = (const float*)d_in[8];
    const float* bo     = (const float*)d_in[9];
    float* out = (float*)d_out;

    char* ws = (char*)d_ws;
    int*   lengths = (int*)(ws + 0);
    int*   bar     = (int*)(ws + 256);       // 32 ints, inside lengths' 1 KB slot
    float* shiftb  = (float*)(ws + 1024);
    float* scaleb  = shiftb + NROWS * DD;
    float* projx   = scaleb + NROWS * DD;
    float* h_out   = projx  + NROWS * DD;                          // 1 MB fp32
    unsigned short* h_bf = (unsigned short*)(h_out + NROWS * DD);  // 512 KB
    unsigned short* Wf   = h_bf + NROWS * DD;                      // 1 MB
    unsigned short* Pf   = Wf + 524288;                            // 4 MB
    unsigned short* Af   = Pf + 2097152;                           // 1 MB
    unsigned short* Wof  = Af + 524288;                            // 128 KB

    hipMemsetAsync(h_bf, 0, (size_t)NROWS * DD * sizeof(unsigned short), stream);
    k_prep<<<929, 256, 0, stream>>>(tokens, A, emb, Wp, Wi, bi, Wo,
                                    Wf, Af, Wof, shiftb, scaleb, projx, lengths, bar);
    void* kargs[] = { (void*)&Af, (void*)&Pf, (void*)&projx, (void*)&shiftb, (void*)&scaleb,
                      (void*)&Wf, (void*)&bp, (void*)&Wof, (void*)&bo, (void*)&lengths,
                      (void*)&h_out, (void*)&h_bf, (void*)&root, (void*)&out, (void*)&bar };
    hipLaunchCooperativeKernel((const void*)k_loop, dim3(128), dim3(1024), kargs, 0, stream);
}

// Round 3
// 2913.584 us; speedup vs baseline: 1.7634x; 1.6677x over previous
//
#include <hip/hip_runtime.h>
#include <hip/hip_bf16.h>

// WeightedGNN forward, MI355X. Round 8: persistent cooperative kernel, v3.
// Rounds 6/7 failed at ~4.8-5.1 ms with FETCH ~3.5 GB regardless of fences ->
// causes narrowed to {barrier false-sharing at the coherence point, sc1 volume
// /redundancy, L2 thrash}. This round: (a) per-batch barrier words padded to
// 256 B + s_sleep(8) polls; (b) h passes through global in FRAGMENT layout,
// staged once per block into LDS (32 KB coalesced sc1, no 4x wave redundancy);
// (c) half of each block's W_proj chunk pinned in LDS once (immune to L2);
// (d) phase-P LayerNorm moved to an in-register fragment reduction (~5x fewer
// VALU ops than the row-gather+6-step-shuffle version).
// Sync protocol itself is unchanged from the twice-passing round-7 kernel.
// B=16, L=64, D=256, NRELS=8.

#define DD 256
#define LLEN 64
#define BBAT 16
#define NROWS 1024   // B*L

typedef __attribute__((ext_vector_type(8))) short short8;   // 8 bf16 = 4 VGPRs
typedef __attribute__((ext_vector_type(4))) float f32x4;
typedef unsigned long long u64;

__device__ inline unsigned short f2bf(float x) {
    unsigned int u = __float_as_uint(x);
    unsigned int r = (u + 0x7fffu + ((u >> 16) & 1u)) >> 16;
    return (unsigned short)r;
}

// ---- coherent (agent-scope, relaxed) 16B accesses: bypass L1/L2, no fences --
__device__ inline short8 ld_coh16(const unsigned short* p) {
    union { short8 v; u64 q[2]; } r;
    r.q[0] = __hip_atomic_load((const u64*)p,     __ATOMIC_RELAXED, __HIP_MEMORY_SCOPE_AGENT);
    r.q[1] = __hip_atomic_load((const u64*)p + 1, __ATOMIC_RELAXED, __HIP_MEMORY_SCOPE_AGENT);
    return r.v;
}
__device__ inline void st_coh16(unsigned short* p, short8 v) {
    union { short8 v; u64 q[2]; } r; r.v = v;
    __hip_atomic_store((u64*)p,     r.q[0], __ATOMIC_RELAXED, __HIP_MEMORY_SCOPE_AGENT);
    __hip_atomic_store((u64*)p + 1, r.q[1], __ATOMIC_RELAXED, __HIP_MEMORY_SCOPE_AGENT);
}

// ---------------- per-batch 8-block barrier (fence-free, padded) --------------
// Each batch's (ctr,gen) lives in its own 256-B slot (bar + b*64 ints) so the
// 16 batches' polls/adds never share a line at the coherence point.
__device__ inline void batch_bar(int* ctr, int* gen) {
    __syncthreads();
    if (threadIdx.x == 0) {
        asm volatile("s_waitcnt vmcnt(0)" ::: "memory");
        int g = __hip_atomic_load(gen, __ATOMIC_RELAXED, __HIP_MEMORY_SCOPE_AGENT);
        int prev = __hip_atomic_fetch_add(ctr, 1, __ATOMIC_RELAXED, __HIP_MEMORY_SCOPE_AGENT);
        if (prev == 7) {
            __hip_atomic_store(ctr, 0, __ATOMIC_RELAXED, __HIP_MEMORY_SCOPE_AGENT);
            __hip_atomic_store(gen, g + 1, __ATOMIC_RELAXED, __HIP_MEMORY_SCOPE_AGENT);
        } else {
            int spins = 0;
            while (__hip_atomic_load(gen, __ATOMIC_RELAXED, __HIP_MEMORY_SCOPE_AGENT) == g) {
                __builtin_amdgcn_s_sleep(8);
                if (++spins > (1 << 20)) break;   // escape hatch; never hit when co-resident
            }
        }
    }
    __syncthreads();
    __builtin_amdgcn_sched_barrier(0);
}

// ---------------- fused one-time prep: cvtW | cvtA | cvtWo | inproj | setup ---
__global__ __launch_bounds__(256) void k_prep(
    const int* __restrict__ tokens, const float* __restrict__ A,
    const float* __restrict__ emb,
    const float* __restrict__ Wp, const float* __restrict__ Wi,
    const float* __restrict__ bi, const float* __restrict__ Wo,
    unsigned short* __restrict__ Wf, unsigned short* __restrict__ Af,
    unsigned short* __restrict__ Wof,
    float* __restrict__ shiftb, float* __restrict__ scaleb, float* __restrict__ projx,
    int* __restrict__ lengths, int* __restrict__ bar)
{
    __shared__ float xs[8][DD];
    const int tid = threadIdx.x;
    const int bid = blockIdx.x;

    if (bid < 256) {
        // ---- W_proj [256][2048] fp32 -> bf16 B-fragment layout ----
        int t = bid * 256 + tid;   // 65536
        int l = t & 63; int rest = t >> 6;
        int tk = rest & 7; rest >>= 3;
        int tn = rest & 15; int hh = rest >> 4;
        int kbase = tk * 32 + (l >> 4) * 8;
        int n = hh * 256 + tn * 16 + (l & 15);
        union { short8 v; unsigned short u[8]; } pk;
#pragma unroll
        for (int j = 0; j < 8; ++j) pk.u[j] = f2bf(Wp[(kbase + j) * 2048 + n]);
        *(short8*)(Wf + (long)t * 8) = pk.v;
    } else if (bid < 512) {
        // ---- A_rels -> bf16 A-fragment layout, K-order k = h*64 + i ----
        int t = (bid - 256) * 256 + tid;   // 65536
        int lane = t & 63;
        int tk = (t >> 6) & 15;
        int jg = (t >> 10) & 3;
        int b  = t >> 12;
        int j = jg * 16 + (lane & 15);
        int kbase = tk * 32 + (lane >> 4) * 8;
        int h  = kbase >> 6;
        int i0 = kbase & 63;
        union { short8 v; unsigned short u[8]; } pk;
#pragma unroll
        for (int jj = 0; jj < 8; ++jj)
            pk.u[jj] = f2bf(A[((long)(b * 64 + i0 + jj) * 64 + j) * 8 + h]);
        *(short8*)(Af + (long)t * 8) = pk.v;
    } else if (bid < 544) {
        // ---- W_out [256][256] fp32 -> bf16 B-fragment layout ----
        int t = (bid - 512) * 256 + tid;   // 8192
        int lane = t & 63;
        int tk = (t >> 6) & 7;
        int nt = t >> 9;
        int kbase = tk * 32 + (lane >> 4) * 8;
        int n = nt * 16 + (lane & 15);
        union { short8 v; unsigned short u[8]; } pk;
#pragma unroll
        for (int j = 0; j < 8; ++j) pk.u[j] = f2bf(Wo[(kbase + j) * 256 + n]);
        *(short8*)(Wof + (long)t * 8) = pk.v;
    } else if (bid < 928) {
        // ---- in_proj: gather emb + [1024x256]@[256x768], 384 blocks ----
        int lb = bid - 544;
        int rowx = lb & 127, nc = lb >> 7;    // nc: 0=shift 1=scale 2=projx
        const int row0 = rowx * 8;
        for (int r = 0; r < 8; ++r) {
            int row = row0 + r;
            int b = row >> 6, l = row & 63;
            int tok = tokens[l * BBAT + b];
            xs[r][tid] = emb[(long)tok * DD + tid];
        }
        __syncthreads();
        const int col = nc * 256 + tid;
        float a[8];
#pragma unroll
        for (int r = 0; r < 8; ++r) a[r] = 0.f;
#pragma unroll 4
        for (int k = 0; k < DD; ++k) {
            float wv = Wi[k * 768 + col];
#pragma unroll
            for (int r = 0; r < 8; ++r) a[r] = fmaf(xs[r][k], wv, a[r]);
        }
        const float bia = bi[col];
        float* dst = (nc == 0) ? shiftb : (nc == 1) ? scaleb : projx;
#pragma unroll
        for (int r = 0; r < 8; ++r) dst[(row0 + r) * DD + tid] = a[r] + bia;
    } else {
        // ---- lengths[b] + padded barrier-state init (16 x 64 ints) ----
        for (int i = tid; i < 1024; i += 256) bar[i] = 0;
        if (tid < BBAT) {
            int c = 0;
            for (int l = 0; l < LLEN; ++l) c += (tokens[l * BBAT + tid] != 0) ? 1 : 0;
            lengths[tid] = c;
        }
    }
}

// ---------------- persistent 64-iteration recurrence kernel -------------------
// grid 128: bid = (b&7) + 8*q + 64*(b>>3); q in [0,8). All blocks: phase P for
// rel-chunk hh=q (16 waves = 4 ig x 4 wv). Blocks q<4: phase A with jg=q.
// h crosses iterations in FRAGMENT layout via h_fg (sc1), staged into LDS.
__global__ __launch_bounds__(1024) void k_loop(
    const unsigned short* __restrict__ Af,     // [16][4][16][64][8]
    unsigned short* __restrict__ Pf,           // [16][16 tk1][16 nt][64][8]
    const float* __restrict__ projx,
    const float* __restrict__ shiftb,
    const float* __restrict__ scaleb,
    const unsigned short* __restrict__ Wf,     // fragment-packed W_proj
    const float* __restrict__ bp,              // [2048]
    const unsigned short* __restrict__ Wof,    // [16 nt][8 tk][64][8]
    const float* __restrict__ bout,
    const int* __restrict__ lengths,
    float* __restrict__ h_out,                 // [1024][256] fp32 (last iter)
    unsigned short* __restrict__ h_fg,         // [16 b][4 ig][8 tk][64][8] bf16 frags
    int* __restrict__ bar)
{
    __shared__ __align__(16) unsigned short w_lds[32768];   // 64 KB: Wf chunk, tk 0..3 (pinned)
    __shared__ __align__(16) unsigned short h_lds[16384];   // 32 KB: h frags (per iter)
    __shared__ float part4[4][64][2];                       // 2 KB: LN cross-wave partials
    __shared__ __align__(16) char scr_raw[33024];           // 32.25 KB scratch (P: sln | A: CsA/hsb/partA)
    unsigned short (*sln)[258] = (unsigned short(*)[258])scr_raw;
    float (*CsA)[260]          = (float(*)[260])scr_raw;                       // 16640 B
    unsigned short (*hsbp)[264] = (unsigned short(*)[264])(scr_raw + 16640);   // 8448 B
    float (*partA)[4][2]       = (float(*)[4][2])(scr_raw + 25088);            // 512 B

    const int t = threadIdx.x;
    const int w = t >> 6, lane = t & 63;
    const int bid = blockIdx.x;
    const int t2 = bid >> 3;
    const int q = t2 & 7;
    const int b = (bid & 7) + 8 * (t2 >> 3);
    const int hh = q;
    int* ctr = bar + b * 64;
    int* gen = bar + b * 64 + 1;
    const int len_b = lengths[b];

    // phase-P constants
    const int ig = w >> 2, wv = w & 3;
    const int r4 = (lane >> 4) * 4;
    const unsigned short* wBase = Wf + ((long)(hh * 16 + wv * 4) * 8) * 512 + lane * 8;
    const int g2 = t >> 8;            // pack: i-quad
    const int tc = t & 255;           // pack: column
    float bpv[4];
#pragma unroll
    for (int tn = 0; tn < 4; ++tn)
        bpv[tn] = bp[hh * 256 + wv * 64 + tn * 16 + (lane & 15)];
    // phase-A constants
    const int d = t & 255;
    const int rbase = (w >> 2) * 4;
    const int dseg = w & 3;

    // ---- pin half of this block's Wf chunk (tk 0..3) in LDS, once ----
    {
        int lt = t >> 4;                  // 0..63 tiles: j = lt>>2, tk = lt&3
        int j = lt >> 2, tk = lt & 3;
        const unsigned short* src = Wf + ((long)(hh * 16 + j) * 8 + tk) * 512 + (t & 15) * 32;
        unsigned short* dst = w_lds + lt * 512 + (t & 15) * 32;
#pragma unroll
        for (int i = 0; i < 4; ++i)
            *(short8*)(dst + i * 8) = *(const short8*)(src + i * 8);
    }
    __syncthreads();

    for (int it = 0; it < 64; ++it) {
        // ================= phase P: Pf = LN_perchunk(h @ W_proj + bp) =========
        // stage h[b] frags: 32 KB coalesced sc1, no redundancy
        {
            const unsigned short* hs = h_fg + (long)b * 16384 + t * 16;
            short8 h0 = ld_coh16(hs);
            short8 h1 = ld_coh16(hs + 8);
            *(short8*)(h_lds + t * 16) = h0;
            *(short8*)(h_lds + t * 16 + 8) = h1;
        }
        __syncthreads();
        f32x4 acc[4];
#pragma unroll
        for (int tn = 0; tn < 4; ++tn) acc[tn] = (f32x4){0.f, 0.f, 0.f, 0.f};
        short8 a8[8];
#pragma unroll
        for (int tk = 0; tk < 8; ++tk)
            a8[tk] = *(const short8*)(h_lds + ((ig * 8 + tk) * 64 + lane) * 8);
#pragma unroll
        for (int tk = 0; tk < 8; ++tk) {
#pragma unroll
            for (int tn = 0; tn < 4; ++tn) {
                short8 bbv;
                if (tk < 4) bbv = *(const short8*)(w_lds + (((wv * 4 + tn) * 4 + tk) * 64 + lane) * 8);
                else        bbv = *(const short8*)(wBase + (long)(tn * 8 + tk) * 512);
                acc[tn] = __builtin_amdgcn_mfma_f32_16x16x32_bf16(a8[tk], bbv, acc[tn], 0, 0, 0);
            }
        }
        // ---- LayerNorm in-register: frag rows r = ig*16 + r4 + r, 4 cols/lane
        float vals[4][4];
#pragma unroll
        for (int tn = 0; tn < 4; ++tn)
#pragma unroll
            for (int r = 0; r < 4; ++r) vals[tn][r] = acc[tn][r] + bpv[tn];
        float s_[4], ss_[4];
#pragma unroll
        for (int r = 0; r < 4; ++r) {
            s_[r]  = (vals[0][r] + vals[1][r]) + (vals[2][r] + vals[3][r]);
            float q0 = vals[0][r] * vals[0][r];
            q0 = fmaf(vals[1][r], vals[1][r], q0);
            q0 = fmaf(vals[2][r], vals[2][r], q0);
            ss_[r] = fmaf(vals[3][r], vals[3][r], q0);
        }
#pragma unroll
        for (int m = 1; m <= 8; m <<= 1) {
#pragma unroll
            for (int r = 0; r < 4; ++r) {
                s_[r]  += __shfl_xor(s_[r], m);
                ss_[r] += __shfl_xor(ss_[r], m);
            }
        }
        if ((lane & 15) == 0) {
#pragma unroll
            for (int r = 0; r < 4; ++r) {
                part4[wv][ig * 16 + r4 + r][0] = s_[r];
                part4[wv][ig * 16 + r4 + r][1] = ss_[r];
            }
        }
        __syncthreads();
#pragma unroll
        for (int r = 0; r < 4; ++r) {
            int row = ig * 16 + r4 + r;
            float s  = (part4[0][row][0] + part4[1][row][0]) + (part4[2][row][0] + part4[3][row][0]);
            float ss = (part4[0][row][1] + part4[1][row][1]) + (part4[2][row][1] + part4[3][row][1]);
            float mean = s * (1.f / 256.f);
            float var  = ss * (1.f / 256.f) - mean * mean;
            float rstd = rsqrtf(var + 1e-5f);
#pragma unroll
            for (int tn = 0; tn < 4; ++tn) {
                float nv = (vals[tn][r] - mean) * rstd;
                sln[row][wv * 64 + tn * 16 + (lane & 15)] = f2bf(nv);
            }
        }
        __syncthreads();
        // ---- pack sln columns -> Pf fragment slots (2 x 16B sc1 per thread)
#pragma unroll
        for (int g = 0; g < 2; ++g) {
            int k0l = g2 * 16 + g * 8;
            union { short8 v; unsigned short u[8]; } pk;
#pragma unroll
            for (int jj = 0; jj < 8; ++jj) pk.u[jj] = sln[k0l + jj][tc];
            int k0 = hh * 64 + k0l;
            int tk1 = k0 >> 5;
            int lane_s = ((k0 >> 3) & 3) * 16 + (tc & 15);
            long off = (long)b * 131072 + tk1 * 8192 + (tc >> 4) * 512 + lane_s * 8;
            st_coh16(Pf + off, pk.v);
        }
        batch_bar(ctr, gen);   // Pf[b] complete & visible

        // ================= phase A: agg + gate + W_out (blocks q<4) ===========
        if (q < 4) {
            const int jg = q;
            const unsigned short* ab = Af + ((long)(b * 4 + jg) * 16) * 512 + lane * 8;
            const unsigned short* pb = Pf + (long)b * 131072 + w * 512 + lane * 8;
            short8 bfr[16];
#pragma unroll
            for (int tk = 0; tk < 16; ++tk)
                bfr[tk] = ld_coh16(pb + (long)tk * 8192);
            f32x4 acc1 = (f32x4){0.f, 0.f, 0.f, 0.f};
#pragma unroll
            for (int tk = 0; tk < 16; ++tk) {
                short8 a = *(const short8*)(ab + (long)tk * 512);
                acc1 = __builtin_amdgcn_mfma_f32_16x16x32_bf16(a, bfr[tk], acc1, 0, 0, 0);
            }
            {
                int n = w * 16 + (lane & 15);
#pragma unroll
                for (int r = 0; r < 4; ++r) CsA[r4 + r][n] = acc1[r];
            }
            __syncthreads();

            float tv[4];
#pragma unroll
            for (int ri = 0; ri < 4; ++ri) {
                int row = b * 64 + jg * 16 + rbase + ri;
                float lin = CsA[rbase + ri][d];
                float shr = lin - tanhf(lin);
                tv[ri] = projx[row * DD + d] + shr;
            }
#pragma unroll
            for (int ri = 0; ri < 4; ++ri) {
                float s = tv[ri], ss = tv[ri] * tv[ri];
#pragma unroll
                for (int m = 32; m >= 1; m >>= 1) { s += __shfl_xor(s, m); ss += __shfl_xor(ss, m); }
                if (lane == 0) { partA[rbase + ri][dseg][0] = s; partA[rbase + ri][dseg][1] = ss; }
            }
            __syncthreads();
#pragma unroll
            for (int ri = 0; ri < 4; ++ri) {
                int r = rbase + ri;
                int row = b * 64 + jg * 16 + r;
                float s  = partA[r][0][0] + partA[r][1][0] + partA[r][2][0] + partA[r][3][0];
                float ss = partA[r][0][1] + partA[r][1][1] + partA[r][2][1] + partA[r][3][1];
                float mean = s * (1.f / 256.f);
                float var  = ss * (1.f / 256.f) - mean * mean;
                float rstd = rsqrtf(var + 1e-5f);
                float nv = (tv[ri] - mean) * rstd;
                float hv = fmaf(shiftb[row * DD + d], nv, scaleb[row * DD + d]);
                hsbp[r][d] = f2bf(fmaxf(hv, 0.f));
            }
            __syncthreads();

            f32x4 acc2 = (f32x4){0.f, 0.f, 0.f, 0.f};
#pragma unroll
            for (int tk = 0; tk < 8; ++tk) {
                short8 a = *(const short8*)(&hsbp[lane & 15][tk * 32 + (lane >> 4) * 8]);
                short8 wfv = *(const short8*)(Wof + (long)(w * 8 + tk) * 512 + lane * 8);
                acc2 = __builtin_amdgcn_mfma_f32_16x16x32_bf16(a, wfv, acc2, 0, 0, 0);
            }
            {
                int n = w * 16 + (lane & 15);
#pragma unroll
                for (int r = 0; r < 4; ++r) CsA[r4 + r][n] = acc2[r];
            }
            __syncthreads();
            const int i_val = 64 - it;
            const bool maskz = (i_val > len_b);
            if (t < 512) {
                int row_l = t >> 5;              // 0..15
                int c0 = (t & 31) * 8;           // 0..248
                f32x4 c0v = *(const f32x4*)&CsA[row_l][c0];
                f32x4 c1v = *(const f32x4*)&CsA[row_l][c0 + 4];
                f32x4 bo0 = *(const f32x4*)&bout[c0];
                f32x4 bo1 = *(const f32x4*)&bout[c0 + 4];
                union { short8 v; unsigned short u[8]; } pk;
                float ym[8];
#pragma unroll
                for (int j = 0; j < 4; ++j) {
                    float y = tanhf(c0v[j] + bo0[j]);
                    ym[j] = maskz ? 0.f : y;
                    pk.u[j] = f2bf(ym[j]);
                }
#pragma unroll
                for (int j = 0; j < 4; ++j) {
                    float y = tanhf(c1v[j] + bo1[j]);
                    ym[4 + j] = maskz ? 0.f : y;
                    pk.u[4 + j] = f2bf(ym[4 + j]);
                }
                int tkf = c0 >> 5;
                int lane_s = row_l + ((c0 >> 3) & 3) * 16;
                st_coh16(h_fg + (long)b * 16384 + ((jg * 8 + tkf) * 64 + lane_s) * 8, pk.v);
                if (it == 63) {
                    float* hp = h_out + ((long)(b * 64 + jg * 16 + row_l)) * DD + c0;
                    f32x4 o0 = {ym[0], ym[1], ym[2], ym[3]};
                    f32x4 o1 = {ym[4], ym[5], ym[6], ym[7]};
                    *(f32x4*)hp = o0;
                    *(f32x4*)(hp + 4) = o1;
                }
            }
        }
        batch_bar(ctr, gen);   // h[b] complete & visible for next phase P
    }
}

// ---------------- final: out[b,d] = sum_i h[b,i,d] * root[b,i] ----------------
__global__ __launch_bounds__(256) void k_final(
    const float* __restrict__ h_buf, const float* __restrict__ root,
    float* __restrict__ out)
{
    const int t = threadIdx.x;
    const int b = blockIdx.x;
    float acc = 0.f;
    for (int i = 0; i < LLEN; ++i)
        acc = fmaf(h_buf[(b * 64 + i) * DD + t], root[b * 64 + i], acc);
    out[b * DD + t] = acc;
}

extern "C" void kernel_launch(void* const* d_in, const int* in_sizes, int n_in,
                              void* d_out, int out_size, void* d_ws, size_t ws_size,
                              hipStream_t stream)
{
    const int*   tokens = (const int*)  d_in[0];
    const float* A      = (const float*)d_in[1];
    const float* root   = (const float*)d_in[2];
    const float* emb    = (const float*)d_in[3];
    const float* Wp     = (const float*)d_in[4];
    const float* bp     = (const float*)d_in[5];
    const float* Wi     = (const float*)d_in[6];
    const float* bi     = (const float*)d_in[7];
    const float* Wo     = (const float*)d_in[8];
    const float* bo     = (const float*)d_in[9];
    float* out = (float*)d_out;

    char* ws = (char*)d_ws;
    int*   lengths = (int*)(ws + 0);
    int*   bar     = (int*)(ws + 256);                 // 16 batches x 64 ints (256 B each)
    float* shiftb  = (float*)(ws + 8192);
    float* scaleb  = shiftb + NROWS * DD;
    float* projx   = scaleb + NROWS * DD;
    float* h_out   = projx  + NROWS * DD;                          // 1 MB fp32
    unsigned short* h_fg = (unsigned short*)(h_out + NROWS * DD);  // 512 KB (frag layout)
    unsigned short* Wf   = h_fg + NROWS * DD;                      // 1 MB
    unsigned short* Pf   = Wf + 524288;                            // 4 MB
    unsigned short* Af   = Pf + 2097152;                           // 1 MB
    unsigned short* Wof  = Af + 524288;                            // 128 KB

    hipMemsetAsync(h_fg, 0, (size_t)NROWS * DD * sizeof(unsigned short), stream);
    k_prep<<<929, 256, 0, stream>>>(tokens, A, emb, Wp, Wi, bi, Wo,
                                    Wf, Af, Wof, shiftb, scaleb, projx, lengths, bar);
    void* kargs[] = { (void*)&Af, (void*)&Pf, (void*)&projx, (void*)&shiftb, (void*)&scaleb,
                      (void*)&Wf, (void*)&bp, (void*)&Wof, (void*)&bo, (void*)&lengths,
                      (void*)&h_out, (void*)&h_fg, (void*)&bar };
    hipLaunchCooperativeKernel((const void*)k_loop, dim3(128), dim3(1024), kargs, 0, stream);
    k_final<<<16, 256, 0, stream>>>(h_out, root, out);
}